// Round 1
// baseline (306.387 us; speedup 1.0000x reference)
//
#include <hip/hip_runtime.h>
#include <hip/hip_bf16.h>
#include <math.h>
#include <stdint.h>

typedef __bf16 bf16_t;
typedef __bf16 bf16x8 __attribute__((ext_vector_type(8)));
typedef float  f32x4  __attribute__((ext_vector_type(4)));

#define L_LEN 8192
#define MODES 64
#define NCOMP 128      // 2*MODES (Re | Im)
#define M_ROWS 4096    // B * n_env * ch

// async global->LDS, 16B per lane. LDS dst must be wave-uniform base + lane*16.
__device__ __forceinline__ void g2lds16(const void* g, void* l) {
  __builtin_amdgcn_global_load_lds(
      (__attribute__((address_space(1))) void*)(uintptr_t)(g),
      (__attribute__((address_space(3))) void*)(l), 16, 0, 0);
}

// ---------------------------------------------------------------------------
// Basis tables (regenerated every call; ws is re-poisoned between launches).
// B1t[n][l]  n<64: cos(2*pi*n*l/L)   n>=64: -sin(2*pi*(n-64)*l/L)   [128][8192]
// B1 [l][n]  same values transposed                                  [8192][128]
// Exact phase reduction: (k*l) mod 8192 is exact in integers.
// ---------------------------------------------------------------------------
__global__ void gen_basis(bf16_t* __restrict__ B1t, bf16_t* __restrict__ B1) {
  int id = blockIdx.x * 256 + threadIdx.x;   // 8192*64 threads
  int l = id >> 6;
  int k = id & 63;
  int r = (l * k) & (L_LEN - 1);
  float ang = (float)r * 7.6699039394282061e-4f;  // 2*pi/8192
  float s, c;
  sincosf(ang, &s, &c);
  B1 [l * NCOMP + k]             = (bf16_t)c;
  B1 [l * NCOMP + MODES + k]     = (bf16_t)(-s);
  B1t[(size_t)k * L_LEN + l]           = (bf16_t)c;
  B1t[(size_t)(MODES + k) * L_LEN + l] = (bf16_t)(-s);
}

// ---------------------------------------------------------------------------
// W[e][i][o][k] (complex fp32) = lam[k]*cw[i][o][k] + (1-lam[k])*sum_c codes[e][c]*codew[c][i][o][k]
// ---------------------------------------------------------------------------
__global__ void wmix(const float* __restrict__ codes, const float* __restrict__ comw,
                     const float* __restrict__ codew, const float* __restrict__ fw,
                     float* __restrict__ W) {
  int id = blockIdx.x * 256 + threadIdx.x;   // 8*32*32*64 threads
  int k = id & 63;
  int o = (id >> 6) & 31;
  int i = (id >> 11) & 31;
  int e = id >> 16;
  float lam = fminf(fmaxf(fw[k] * (1.0f / 6.0f) + 0.5f, 0.0f), 1.0f);
  float are = 0.f, aim = 0.f;
#pragma unroll
  for (int c = 0; c < 16; ++c) {
    float cd = codes[e * 16 + c];
    const float* p = codew + ((((c * 32 + i) * 32 + o) * 64 + k) << 1);
    are += cd * p[0];
    aim += cd * p[1];
  }
  const float* q = comw + (((i * 32 + o) * 64 + k) << 1);
  float wre = lam * q[0] + (1.f - lam) * are;
  float wim = lam * q[1] + (1.f - lam) * aim;
  float* dst = W + ((((e * 32 + i) * 32 + o) * 64 + k) << 1);
  dst[0] = wre;
  dst[1] = wim;
}

// ---------------------------------------------------------------------------
// Stage 1: X[4096][128] += x[4096][8192] (bf16) * B1t^T  (split-K GEMM)
// grid = (32 m-tiles, 16 k-splits); block tile 128x128, BK=64, 4 waves of 64x64.
// A staged via ds_write (needs fp32->bf16 cvt), pitch 72 bf16 (pad) -> 2-way banks.
// B staged via global_load_lds with XOR swizzle: element (n, k) lives at
//   Bl byte offset n*128 + ((k>>3) ^ (n&7))*16  -> conflict-free frag reads.
// ---------------------------------------------------------------------------
__global__ __launch_bounds__(256) void stage1(const float* __restrict__ x,
                                              const bf16_t* __restrict__ B1t,
                                              float* __restrict__ X) {
  __shared__ bf16_t Al[128 * 72];   // 18 KiB, row pitch 72 elems (144 B)
  __shared__ bf16_t Bl[128 * 64];   // 16 KiB, row pitch 64 elems (128 B), swizzled
  const int t = threadIdx.x;
  const int lane = t & 63;
  const int w = t >> 6;
  const int wm = w >> 1, wn = w & 1;
  const int mt = blockIdx.x;
  const int sp = blockIdx.y;
  const int lq = lane >> 4;    // quad 0..3
  const int l15 = lane & 15;

  f32x4 acc[4][4];
#pragma unroll
  for (int a = 0; a < 4; ++a)
#pragma unroll
    for (int b = 0; b < 4; ++b) acc[a][b] = (f32x4){0.f, 0.f, 0.f, 0.f};

  const int r = t >> 1, half = t & 1;
  const float* xrow = x + (size_t)(mt * 128 + r) * L_LEN + half * 32;
  bf16_t* adst = Al + r * 72 + half * 32;

  for (int ch = 0; ch < 8; ++ch) {
    const int l0 = sp * 512 + ch * 64;
    __syncthreads();
    // ---- stage A tile: 128 rows x 64 cols, fp32 -> bf16 ----
    const float4* xp = (const float4*)(xrow + l0);
#pragma unroll
    for (int j = 0; j < 4; ++j) {
      float4 p0 = xp[2 * j], p1 = xp[2 * j + 1];
      bf16x8 v = {(bf16_t)p0.x, (bf16_t)p0.y, (bf16_t)p0.z, (bf16_t)p0.w,
                  (bf16_t)p1.x, (bf16_t)p1.y, (bf16_t)p1.z, (bf16_t)p1.w};
      *(bf16x8*)(adst + j * 8) = v;
    }
    // ---- stage B tile: 128 rows x 64 cols bf16, swizzled direct-to-LDS ----
#pragma unroll
    for (int q2 = 0; q2 < 4; ++q2) {
      int slot = t + 256 * q2;       // lds dst = slot*16 (lane-linear per wave)
      int n  = slot >> 3;
      int m8 = slot & 7;
      int j8 = m8 ^ (n & 7);
      g2lds16(B1t + (size_t)n * L_LEN + l0 + j8 * 8, (char*)Bl + slot * 16);
    }
    __syncthreads();
    // ---- MFMA: 2 k-steps x 16 mfma ----
#pragma unroll
    for (int s = 0; s < 2; ++s) {
      bf16x8 a[4], b[4];
#pragma unroll
      for (int mf = 0; mf < 4; ++mf) {
        int row = wm * 64 + mf * 16 + l15;
        a[mf] = *(const bf16x8*)(Al + row * 72 + s * 32 + lq * 8);
      }
#pragma unroll
      for (int nf = 0; nf < 4; ++nf) {
        int n = wn * 64 + nf * 16 + l15;
        int j8 = (s * 4 + lq) ^ (n & 7);
        b[nf] = *(const bf16x8*)(Bl + n * 64 + j8 * 8);
      }
#pragma unroll
      for (int mf = 0; mf < 4; ++mf)
#pragma unroll
        for (int nf = 0; nf < 4; ++nf)
          acc[mf][nf] = __builtin_amdgcn_mfma_f32_16x16x32_bf16(a[mf], b[nf], acc[mf][nf], 0, 0, 0);
    }
  }
  // ---- split-K reduce via fp32 atomics (X pre-zeroed by memset) ----
#pragma unroll
  for (int mf = 0; mf < 4; ++mf)
#pragma unroll
    for (int nf = 0; nf < 4; ++nf) {
      int n = wn * 64 + nf * 16 + l15;
#pragma unroll
      for (int rg = 0; rg < 4; ++rg) {
        int m = mt * 128 + wm * 64 + mf * 16 + lq * 4 + rg;  // C frag: row=(lane>>4)*4+reg, col=lane&15
        atomicAdd(X + (size_t)m * NCOMP + n, acc[mf][nf][rg]);
      }
    }
}

// ---------------------------------------------------------------------------
// Mix: per (b,e) block. Y[b,e,o,k] = sum_i X[b,e,i,k]*W[e,i,o,k], scaled for irfft,
// emitted as bf16 A2[m=(b,e,o)][Re k | Im k].
// ---------------------------------------------------------------------------
__global__ __launch_bounds__(256) void mixk(const float* __restrict__ X,
                                            const float* __restrict__ W,
                                            bf16_t* __restrict__ A2) {
  __shared__ float Xs[32 * 128];
  const int t = threadIdx.x;
  const int be = blockIdx.x;       // b*8+e
  const int e = be & 7;
#pragma unroll
  for (int j = 0; j < 16; ++j) {
    int idx = t + 256 * j;
    Xs[idx] = X[(size_t)be * 4096 + idx];
  }
  __syncthreads();
  const int k = t & 63;
  const int olo = t >> 6;          // o = olo*8 + j
  float yre[8], yim[8];
#pragma unroll
  for (int j = 0; j < 8; ++j) { yre[j] = 0.f; yim[j] = 0.f; }
  for (int i = 0; i < 32; ++i) {
    float xr = Xs[i * 128 + k];
    float xi = Xs[i * 128 + 64 + k];
    const float* wp = W + ((((e * 32 + i) * 32 + olo * 8) * 64 + k) << 1);
#pragma unroll
    for (int j = 0; j < 8; ++j) {
      float2 wv = *(const float2*)(wp + j * 128);
      yre[j] += xr * wv.x - xi * wv.y;
      yim[j] += xr * wv.y + xi * wv.x;
    }
  }
  float sc = (k == 0) ? (1.0f / 8192.0f) : (2.0f / 8192.0f);  // irfft: DC 1/L, others 2/L
#pragma unroll
  for (int j = 0; j < 8; ++j) {
    int m = be * 32 + olo * 8 + j;
    A2[m * NCOMP + k]         = (bf16_t)(yre[j] * sc);
    A2[m * NCOMP + MODES + k] = (bf16_t)(yim[j] * sc);
  }
}

// ---------------------------------------------------------------------------
// Stage 2: out[4096][8192] = A2[4096][128] * B1^T (K=128, loaded once).
// grid = (64 l-tiles, 32 m-tiles); block tile 128x128; 4 waves of 64x64.
// Both operands via global_load_lds with the same XOR swizzle (16 slots/row).
// out[m][l] = sum_k Yre*cos - Yim*sin.
// ---------------------------------------------------------------------------
__global__ __launch_bounds__(256) void stage2(const bf16_t* __restrict__ A2,
                                              const bf16_t* __restrict__ B1,
                                              float* __restrict__ out) {
  __shared__ bf16_t As[128 * 128];   // 32 KiB, swizzled
  __shared__ bf16_t Bs[128 * 128];   // 32 KiB, swizzled
  const int t = threadIdx.x;
  const int lane = t & 63;
  const int w = t >> 6;
  const int wm = w >> 1, wl = w & 1;
  const int lt = blockIdx.x, mt = blockIdx.y;
  const int lq = lane >> 4, l15 = lane & 15;

#pragma unroll
  for (int q2 = 0; q2 < 8; ++q2) {
    int slot = t + 256 * q2;
    int row = slot >> 4;
    int m16 = slot & 15;
    int j8 = m16 ^ (row & 15);
    g2lds16(A2 + (size_t)(mt * 128 + row) * NCOMP + j8 * 8, (char*)As + slot * 16);
  }
#pragma unroll
  for (int q2 = 0; q2 < 8; ++q2) {
    int slot = t + 256 * q2;
    int lr = slot >> 4;
    int m16 = slot & 15;
    int j8 = m16 ^ (lr & 15);
    g2lds16(B1 + (size_t)(lt * 128 + lr) * NCOMP + j8 * 8, (char*)Bs + slot * 16);
  }
  __syncthreads();

  f32x4 acc[4][4];
#pragma unroll
  for (int a = 0; a < 4; ++a)
#pragma unroll
    for (int b = 0; b < 4; ++b) acc[a][b] = (f32x4){0.f, 0.f, 0.f, 0.f};

#pragma unroll
  for (int s = 0; s < 4; ++s) {
    bf16x8 a[4], b[4];
#pragma unroll
    for (int mf = 0; mf < 4; ++mf) {
      int row = wm * 64 + mf * 16 + l15;
      a[mf] = *(const bf16x8*)(As + row * 128 + (((s * 4 + lq) ^ (row & 15)) * 8));
    }
#pragma unroll
    for (int nf = 0; nf < 4; ++nf) {
      int lr = wl * 64 + nf * 16 + l15;
      b[nf] = *(const bf16x8*)(Bs + lr * 128 + (((s * 4 + lq) ^ (lr & 15)) * 8));
    }
#pragma unroll
    for (int mf = 0; mf < 4; ++mf)
#pragma unroll
      for (int nf = 0; nf < 4; ++nf)
        acc[mf][nf] = __builtin_amdgcn_mfma_f32_16x16x32_bf16(a[mf], b[nf], acc[mf][nf], 0, 0, 0);
  }

#pragma unroll
  for (int mf = 0; mf < 4; ++mf)
#pragma unroll
    for (int nf = 0; nf < 4; ++nf) {
      int m = mt * 128 + wm * 64 + mf * 16 + lq * 4;
      int l = lt * 128 + wl * 64 + nf * 16 + l15;
      float* op = out + (size_t)m * L_LEN + l;
#pragma unroll
      for (int rg = 0; rg < 4; ++rg) op[(size_t)rg * L_LEN] = acc[mf][nf][rg];
    }
}

// ---------------------------------------------------------------------------
// ws layout:  [0,2M) B1t bf16 [128][8192]
//             [2M,4M) B1 bf16 [8192][128]
//             [4M,6M) X fp32 [4096][128]
//             [6M,10M) W fp32 [8][32][32][64][2]
//             [10M,11M) A2 bf16 [4096][128]
// ---------------------------------------------------------------------------
extern "C" void kernel_launch(void* const* d_in, const int* in_sizes, int n_in,
                              void* d_out, int out_size, void* d_ws, size_t ws_size,
                              hipStream_t stream) {
  const float* x     = (const float*)d_in[0];
  const float* codes = (const float*)d_in[1];
  const float* comw  = (const float*)d_in[2];
  const float* codew = (const float*)d_in[3];
  const float* fw    = (const float*)d_in[4];
  float* out = (float*)d_out;
  char* ws = (char*)d_ws;
  bf16_t* B1t = (bf16_t*)(ws);
  bf16_t* B1  = (bf16_t*)(ws + (size_t)(2u << 20));
  float*  X   = (float*) (ws + (size_t)(4u << 20));
  float*  W   = (float*) (ws + (size_t)(6u << 20));
  bf16_t* A2  = (bf16_t*)(ws + (size_t)(10u << 20));

  gen_basis<<<2048, 256, 0, stream>>>(B1t, B1);
  wmix<<<2048, 256, 0, stream>>>(codes, comw, codew, fw, W);
  hipMemsetAsync(X, 0, (size_t)M_ROWS * NCOMP * sizeof(float), stream);
  stage1<<<dim3(32, 16), 256, 0, stream>>>(x, B1t, X);
  mixk<<<128, 256, 0, stream>>>(X, W, A2);
  stage2<<<dim3(64, 32), 256, 0, stream>>>(A2, B1, out);
}